// Round 3
// baseline (1023.014 us; speedup 1.0000x reference)
//
#include <hip/hip_runtime.h>
#include <hip/hip_bf16.h>

// GRU scan with sparse resets. T=1024, B=256, D=128, H=128.
// Round 3: MFMA scan. 16 batch elements per block, 16 blocks, 512 thr (8 waves).
// Per step: [x,h] (16x256) @ [Wi;Wh] (256x384) via 24 mfma_f32_16x16x32_f16
// per wave (3 n-tiles each). Wave w owns n-tiles {w, 8+w, 16+w} -> each lane
// holds r,z,n of the SAME hidden column => gate math fully lane-local, carry
// kept in f32 registers (C/D rows (lane>>4)*4+j are re-owned every step).
// h/x tiles in LDS as f16 with XOR swizzle (byte ^= (row&7)<<4) to avoid
// 16-way bank conflicts on ds_read_b128 A-frags. x staged 2 steps ahead
// (issue-early / write-late). One barrier per step.

#define T_STEPS 1024
#define B_SZ 256
#define D_SZ 128
#define H_SZ 128
#define BPB 16
#define NTHR 512

typedef _Float16 f16x8 __attribute__((ext_vector_type(8)));
typedef _Float16 f16x4 __attribute__((ext_vector_type(4)));
typedef float f32x4 __attribute__((ext_vector_type(4)));

__device__ __forceinline__ float fastrcp(float x) {
#if __has_builtin(__builtin_amdgcn_rcpf)
  return __builtin_amdgcn_rcpf(x);
#else
  return 1.0f / x;
#endif
}

// swizzled byte offset of element (row, colf16) in a [16][128] f16 tile
__device__ __forceinline__ int swz_off(int row, int colf16) {
  return row * 256 + (((colf16) * 2) ^ ((row & 7) << 4));
}

__device__ __forceinline__ void store4f16(_Float16* base, int row, int colf16,
                                          float4 v) {
  union { f16x4 h; unsigned long long u; } p;
  p.h[0] = (_Float16)v.x; p.h[1] = (_Float16)v.y;
  p.h[2] = (_Float16)v.z; p.h[3] = (_Float16)v.w;
  *(unsigned long long*)((char*)base + swz_off(row, colf16)) = p.u;
}

__device__ __forceinline__ f16x8 read_frag(const _Float16* base, int s, int q,
                                           int kk) {
  // A-frag for mfma 16x16x32: row = lane&15 (=s), k = (lane>>4)*8.. (=q*8)
  return *(const f16x8*)((const char*)base + swz_off(s, kk * 32 + q * 8));
}

__global__ __launch_bounds__(NTHR, 2)
void gru_mfma_kernel(const float* __restrict__ seq,
                     const int* __restrict__ resets,
                     const float* __restrict__ h0,
                     const float* __restrict__ Wi,
                     const float* __restrict__ Wh,
                     const float* __restrict__ bh,
                     float* __restrict__ out) {
  const int bb = blockIdx.x * BPB;
  const int tid = threadIdx.x;
  const int w = tid >> 6;
  const int lane = tid & 63;
  const int q = lane >> 4;        // k-chunk / C-row group
  const int s = lane & 15;        // A row / B,C col within tile
  const int ch = w * 16 + s;      // hidden column 0..127 owned by this lane

  __shared__ unsigned int rstm[T_STEPS];                  // 4 KB reset bitmasks
  __shared__ __align__(16) _Float16 xt[3][BPB * H_SZ];    // 12 KB, swizzled
  __shared__ __align__(16) _Float16 ht[2][BPB * H_SZ];    // 8 KB, swizzled

  // ---- prologue: reset bitmask (bit j = resets[t][bb+j]) ----
  for (int tt = tid; tt < T_STEPS; tt += NTHR) {
    const int* rp = &resets[(size_t)tt * B_SZ + bb];
    unsigned m = 0;
#pragma unroll
    for (int j = 0; j < BPB; j++) m |= (rp[j] != 0 ? 1u : 0u) << j;
    rstm[tt] = m;
  }

  // ---- B-fragments (weights) -> registers ----
  // B-frag layout: col = lane&15 (tile col), k = (lane>>4)*8 + j.
  // wave w's tiles: {w, 8+w, 16+w} -> W columns {ch, 128+ch, 256+ch}.
  f16x8 wiF[3][4], whF[3][4];
#pragma unroll
  for (int g3 = 0; g3 < 3; g3++) {
    const int col = g3 * H_SZ + ch;
#pragma unroll
    for (int kk = 0; kk < 4; kk++) {
      f16x8 a, b;
#pragma unroll
      for (int j = 0; j < 8; j++) {
        const int k = kk * 32 + q * 8 + j;
        a[j] = (_Float16)Wi[(size_t)k * 384 + col];
        b[j] = (_Float16)Wh[(size_t)k * 384 + col];
      }
      wiF[g3][kk] = a;
      whF[g3][kk] = b;
    }
  }

  const float bhr = bh[ch];
  const float bhz = bh[H_SZ + ch];
  const float bhn = bh[2 * H_SZ + ch];

  float h0reg[4], hu[4];
#pragma unroll
  for (int j = 0; j < 4; j++) {
    h0reg[j] = h0[(size_t)(bb + q * 4 + j) * H_SZ + ch];
    hu[j] = h0reg[j];   // h_eff(0) = h0 (reset at t=0 is a no-op on h0)
  }

  // ---- stage ht[0] (= h0 tile) and xt[0], xt[1] ----
  {
    const int e0 = tid * 4;          // 2048 f16 elems per tile / 512 thr
    const int row = e0 >> 7, col0 = e0 & 127;
    float4 hv = *(const float4*)&h0[(size_t)(bb + row) * H_SZ + col0];
    store4f16(ht[0], row, col0, hv);
    float4 x0 = *(const float4*)&seq[((size_t)0 * B_SZ + bb + row) * D_SZ + col0];
    store4f16(xt[0], row, col0, x0);
    float4 x1 = *(const float4*)&seq[((size_t)1 * B_SZ + bb + row) * D_SZ + col0];
    store4f16(xt[1], row, col0, x1);
  }
  __syncthreads();

  float* ys = out + (size_t)B_SZ * H_SZ;   // out = [final_carry] ++ [ys]
  const int e0 = tid * 4;
  const int srow = e0 >> 7, scol = e0 & 127;

  int rdx = 0, wrx = 2, hp = 0;            // xt read, xt write, ht read bufs

#pragma unroll 1
  for (int t = 0; t < T_STEPS; t++) {
    // issue x[t+2] global load early (consumed after the MFMA+gates phase)
    int tl = t + 2; if (tl > T_STEPS - 1) tl = T_STEPS - 1;
    float4 xs = *(const float4*)&seq[((size_t)tl * B_SZ + bb + srow) * D_SZ + scol];

    const _Float16* xb = xt[rdx];
    const _Float16* hb = ht[hp];
    f16x8 xf[4], hf[4];
#pragma unroll
    for (int kk = 0; kk < 4; kk++) xf[kk] = read_frag(xb, s, q, kk);
#pragma unroll
    for (int kk = 0; kk < 4; kk++) hf[kk] = read_frag(hb, s, q, kk);

    f32x4 aR = {0.f, 0.f, 0.f, 0.f}, aZ = {0.f, 0.f, 0.f, 0.f};
    f32x4 aIN = {0.f, 0.f, 0.f, 0.f}, aHN = {0.f, 0.f, 0.f, 0.f};
    // x-part first: can issue as soon as xf lands, overlapping hf reads
#pragma unroll
    for (int kk = 0; kk < 4; kk++) {
      aR  = __builtin_amdgcn_mfma_f32_16x16x32_f16(xf[kk], wiF[0][kk], aR, 0, 0, 0);
      aZ  = __builtin_amdgcn_mfma_f32_16x16x32_f16(xf[kk], wiF[1][kk], aZ, 0, 0, 0);
      aIN = __builtin_amdgcn_mfma_f32_16x16x32_f16(xf[kk], wiF[2][kk], aIN, 0, 0, 0);
    }
#pragma unroll
    for (int kk = 0; kk < 4; kk++) {
      aR  = __builtin_amdgcn_mfma_f32_16x16x32_f16(hf[kk], whF[0][kk], aR, 0, 0, 0);
      aZ  = __builtin_amdgcn_mfma_f32_16x16x32_f16(hf[kk], whF[1][kk], aZ, 0, 0, 0);
      aHN = __builtin_amdgcn_mfma_f32_16x16x32_f16(hf[kk], whF[2][kk], aHN, 0, 0, 0);
    }

    const unsigned rn = rstm[(t + 1) & (T_STEPS - 1)];
    _Float16* hw = ht[hp ^ 1];
#pragma unroll
    for (int j = 0; j < 4; j++) {
      const int row = q * 4 + j;
      const float ar = aR[j] + bhr;
      const float az = aZ[j] + bhz;
      const float ahn = aHN[j] + bhn;
      const float r = fastrcp(1.f + __expf(-ar));
      const float z = fastrcp(1.f + __expf(-az));
      float ta = aIN[j] + r * ahn;
      ta = fminf(fmaxf(ta, -15.f), 15.f);
      const float e2 = __expf(2.f * ta);
      const float n = (e2 - 1.f) * fastrcp(e2 + 1.f);
      const float hnew = n + z * (hu[j] - n);

      ys[((size_t)t * B_SZ + bb + row) * H_SZ + ch] = hnew;
      if (t == T_STEPS - 1) out[(size_t)(bb + row) * H_SZ + ch] = hnew;

      const float heff = ((rn >> row) & 1u) ? h0reg[j] : hnew;
      hu[j] = heff;
      *(_Float16*)((char*)hw + swz_off(row, ch)) = (_Float16)heff;
    }

    // write-late half of the x[t+2] stage
    store4f16(xt[wrx], srow, scol, xs);

    __syncthreads();
    rdx = (rdx == 2) ? 0 : rdx + 1;
    wrx = (wrx == 2) ? 0 : wrx + 1;
    hp ^= 1;
  }
}

extern "C" void kernel_launch(void* const* d_in, const int* in_sizes, int n_in,
                              void* d_out, int out_size, void* d_ws, size_t ws_size,
                              hipStream_t stream) {
  const float* seq    = (const float*)d_in[0];
  const int*   resets = (const int*)d_in[1];
  const float* h0     = (const float*)d_in[2];
  const float* Wi     = (const float*)d_in[3];
  const float* Wh     = (const float*)d_in[4];
  const float* bh     = (const float*)d_in[5];
  (void)in_sizes; (void)n_in; (void)d_ws; (void)ws_size; (void)out_size;

  gru_mfma_kernel<<<B_SZ / BPB, NTHR, 0, stream>>>(seq, resets, h0, Wi, Wh, bh,
                                                   (float*)d_out);
}